// Round 1
// baseline (1027.566 us; speedup 1.0000x reference)
//
#include <hip/hip_runtime.h>

// ---------------------------------------------------------------------------
// SelfAttention (column-softmax variant):
//   q,k,v = X @ W  -> (B,H,T,E) layout
//   D[d,t] = k_d . q_t / sqrt(E)   (per b,h)
//   P = row_softmax(D)             (normalize over t for each d == ref axis=2)
//   out[t] = sum_d P[d,t] * v[d]   ; final = out @ Wu + bu
// Two-pass: stats kernel (m_d, s_d over all t), then apply kernel.
// Round 0: correct fp32 baseline, register-tiled LDS GEMM bodies.
// ---------------------------------------------------------------------------

constexpr int B_ = 4;
constexpr int T_ = 2048;
constexpr int H_ = 8;
constexpr int E_ = 64;
constexpr float SCALE_ = 0.125f;  // 1/sqrt(64), folded into Q projection
constexpr int PAD = 68;           // LDS row stride (floats): 16B-aligned, bank-spread

// ---- projection: Y[((b*H+h)*T+t)*64+e] = scale * sum_c X[b,t,c]*W[c, h*64+e]
__global__ __launch_bounds__(512) void proj_kernel(
    const float* __restrict__ X, const float* __restrict__ W,
    float* __restrict__ Y, float scale) {
  constexpr int RT = 8;
  __shared__ float xs[RT][E_];
  const int row0 = blockIdx.x * RT;  // row = b*T + t
  const int tid = threadIdx.x;
  {
    const int r = tid >> 6, c = tid & 63;
    xs[r][c] = X[(row0 + r) * E_ + c];
  }
  __syncthreads();
  const int j = tid;                 // output col 0..511
  const int h = j >> 6, e = j & 63;
  float acc[RT];
#pragma unroll
  for (int r = 0; r < RT; ++r) acc[r] = 0.f;
  for (int c = 0; c < E_; ++c) {
    const float w = W[c * (H_ * E_) + j];
#pragma unroll
    for (int r = 0; r < RT; ++r) acc[r] += xs[r][c] * w;
  }
#pragma unroll
  for (int r = 0; r < RT; ++r) {
    const int row = row0 + r;
    const int b = row >> 11;         // / T_
    const int t = row & (T_ - 1);
    Y[(((size_t)(b * H_ + h) * T_ + t) << 6) + e] = acc[r] * scale;
  }
}

// ---- pass A: per (b,h,d): m_d = max_t k_d.q_t ; s_d = sum_t exp(.-m_d)
__global__ __launch_bounds__(256) void stats_kernel(
    const float* __restrict__ Kmat, const float* __restrict__ Qmat,
    float* __restrict__ m_ws, float* __restrict__ s_ws) {
  __shared__ float ks[64][PAD];
  __shared__ float qs[64][PAD];
  const int bh = blockIdx.y;
  const int d0 = blockIdx.x * 64;
  const float* Kb = Kmat + (size_t)bh * T_ * E_;
  const float* Qb = Qmat + (size_t)bh * T_ * E_;
  const int tid = threadIdx.x;
  const int tx = tid & 15, ty = tid >> 4;

  for (int idx = tid; idx < 64 * 16; idx += 256) {
    const int r = idx >> 4, c4 = idx & 15;
    *(float4*)&ks[r][c4 * 4] = *(const float4*)&Kb[(size_t)(d0 + r) * E_ + c4 * 4];
  }

  float m_run[4], s_run[4];
#pragma unroll
  for (int i = 0; i < 4; ++i) { m_run[i] = -1e30f; s_run[i] = 0.f; }

  for (int t0 = 0; t0 < T_; t0 += 64) {
    __syncthreads();
    for (int idx = tid; idx < 64 * 16; idx += 256) {
      const int r = idx >> 4, c4 = idx & 15;
      *(float4*)&qs[r][c4 * 4] = *(const float4*)&Qb[(size_t)(t0 + r) * E_ + c4 * 4];
    }
    __syncthreads();

    float acc[4][4];
#pragma unroll
    for (int i = 0; i < 4; ++i)
#pragma unroll
      for (int j = 0; j < 4; ++j) acc[i][j] = 0.f;

#pragma unroll
    for (int c4 = 0; c4 < 16; ++c4) {
      float4 kv[4], qv[4];
#pragma unroll
      for (int i = 0; i < 4; ++i) kv[i] = *(const float4*)&ks[ty + 16 * i][c4 * 4];
#pragma unroll
      for (int j = 0; j < 4; ++j) qv[j] = *(const float4*)&qs[tx + 16 * j][c4 * 4];
#pragma unroll
      for (int i = 0; i < 4; ++i)
#pragma unroll
        for (int j = 0; j < 4; ++j)
          acc[i][j] += kv[i].x * qv[j].x + kv[i].y * qv[j].y +
                       kv[i].z * qv[j].z + kv[i].w * qv[j].w;
    }

#pragma unroll
    for (int i = 0; i < 4; ++i) {
      const float mx = fmaxf(fmaxf(acc[i][0], acc[i][1]),
                             fmaxf(acc[i][2], acc[i][3]));
      const float m_new = fmaxf(m_run[i], mx);
      const float s_add = __expf(acc[i][0] - m_new) + __expf(acc[i][1] - m_new) +
                          __expf(acc[i][2] - m_new) + __expf(acc[i][3] - m_new);
      s_run[i] = s_run[i] * __expf(m_run[i] - m_new) + s_add;
      m_run[i] = m_new;
    }
  }

  // combine the 16 tx-lanes (consecutive lanes) that share each d
#pragma unroll
  for (int i = 0; i < 4; ++i) {
#pragma unroll
    for (int mask = 1; mask < 16; mask <<= 1) {
      const float m2 = __shfl_xor(m_run[i], mask);
      const float s2 = __shfl_xor(s_run[i], mask);
      const float m_new = fmaxf(m_run[i], m2);
      s_run[i] = s_run[i] * __expf(m_run[i] - m_new) + s2 * __expf(m2 - m_new);
      m_run[i] = m_new;
    }
  }
  if (tx == 0) {
#pragma unroll
    for (int i = 0; i < 4; ++i) {
      const int d = d0 + ty + 16 * i;
      m_ws[(size_t)bh * T_ + d] = m_run[i];
      s_ws[(size_t)bh * T_ + d] = s_run[i];
    }
  }
}

// ---- pass B: out[t,e] = sum_d exp(k_d.q_t - m_d)/s_d * v[d,e]
__global__ __launch_bounds__(256) void apply_kernel(
    const float* __restrict__ Kmat, const float* __restrict__ Qmat,
    const float* __restrict__ Vmat, const float* __restrict__ m_ws,
    const float* __restrict__ s_ws, float* __restrict__ o_ws) {
  __shared__ float qs[64][PAD];  // Q t-tile        (17.4 KB)
  __shared__ float ks[32][PAD];  // K d-chunk       ( 8.7 KB)
  __shared__ float vs[32][E_];   // V d-chunk       ( 8.0 KB)
  __shared__ float ps[32][64];   // P[d][t] tile    ( 8.0 KB)
  const int bh = blockIdx.y;
  const int b = bh >> 3, h = bh & 7;
  const int t0 = blockIdx.x * 64;
  const float* Kb = Kmat + (size_t)bh * T_ * E_;
  const float* Qb = Qmat + (size_t)bh * T_ * E_;
  const float* Vb = Vmat + (size_t)bh * T_ * E_;
  const float* m_stat = m_ws + (size_t)bh * T_;
  const float* s_stat = s_ws + (size_t)bh * T_;
  const int tid = threadIdx.x;
  const int tx = tid & 15, ty = tid >> 4;

  for (int idx = tid; idx < 64 * 16; idx += 256) {
    const int r = idx >> 4, c4 = idx & 15;
    *(float4*)&qs[r][c4 * 4] = *(const float4*)&Qb[(size_t)(t0 + r) * E_ + c4 * 4];
  }

  float acc[4][4];  // out[t = ty*4+i][e = tx*4+j]
#pragma unroll
  for (int i = 0; i < 4; ++i)
#pragma unroll
    for (int j = 0; j < 4; ++j) acc[i][j] = 0.f;

  for (int d0 = 0; d0 < T_; d0 += 32) {
    __syncthreads();
    for (int idx = tid; idx < 32 * 16; idx += 256) {
      const int r = idx >> 4, c4 = idx & 15;
      *(float4*)&ks[r][c4 * 4] = *(const float4*)&Kb[(size_t)(d0 + r) * E_ + c4 * 4];
      *(float4*)&vs[r][c4 * 4] = *(const float4*)&Vb[(size_t)(d0 + r) * E_ + c4 * 4];
    }
    __syncthreads();

    // phase 1: P[d][t] for d-chunk (d = ty+16i, t = tx+16j)
    float dacc[2][4];
#pragma unroll
    for (int i = 0; i < 2; ++i)
#pragma unroll
      for (int j = 0; j < 4; ++j) dacc[i][j] = 0.f;

#pragma unroll
    for (int c4 = 0; c4 < 16; ++c4) {
      float4 kv[2], qv[4];
#pragma unroll
      for (int i = 0; i < 2; ++i) kv[i] = *(const float4*)&ks[ty + 16 * i][c4 * 4];
#pragma unroll
      for (int j = 0; j < 4; ++j) qv[j] = *(const float4*)&qs[tx + 16 * j][c4 * 4];
#pragma unroll
      for (int i = 0; i < 2; ++i)
#pragma unroll
        for (int j = 0; j < 4; ++j)
          dacc[i][j] += kv[i].x * qv[j].x + kv[i].y * qv[j].y +
                        kv[i].z * qv[j].z + kv[i].w * qv[j].w;
    }
#pragma unroll
    for (int i = 0; i < 2; ++i) {
      const int d = d0 + ty + 16 * i;
      const float mi = m_stat[d];
      const float is = 1.0f / s_stat[d];
#pragma unroll
      for (int j = 0; j < 4; ++j)
        ps[ty + 16 * i][tx + 16 * j] = __expf(dacc[i][j] - mi) * is;
    }
    __syncthreads();

    // phase 2: acc[t][e] += sum_d P[d][t] * V[d][e]
    for (int d = 0; d < 32; ++d) {
      const float4 p4 = *(const float4*)&ps[d][ty * 4];
      const float4 v4 = *(const float4*)&vs[d][tx * 4];
      const float pv[4] = {p4.x, p4.y, p4.z, p4.w};
      const float vv[4] = {v4.x, v4.y, v4.z, v4.w};
#pragma unroll
      for (int i = 0; i < 4; ++i)
#pragma unroll
        for (int j = 0; j < 4; ++j) acc[i][j] += pv[i] * vv[j];
    }
  }

  // write o_ws in (b, t, h, e) layout
#pragma unroll
  for (int i = 0; i < 4; ++i) {
    const int t = t0 + ty * 4 + i;
    float4 o4 = make_float4(acc[i][0], acc[i][1], acc[i][2], acc[i][3]);
    *(float4*)&o_ws[((size_t)(b * T_ + t) * H_ + h) * E_ + tx * 4] = o4;
  }
}

// ---- unify: out[row, j] = sum_c o_ws[row, c] * Wu[c, j] + bu[j]
__global__ __launch_bounds__(256) void unify_kernel(
    const float* __restrict__ o_ws, const float* __restrict__ Wu,
    const float* __restrict__ bu, float* __restrict__ out) {
  constexpr int RT = 16;
  __shared__ float xs[RT][H_ * E_];  // 32 KB
  const int row0 = blockIdx.x * RT;
  const int tid = threadIdx.x;
  for (int idx = tid; idx < RT * 128; idx += 256) {
    const int r = idx >> 7, c4 = idx & 127;
    *(float4*)&xs[r][c4 * 4] = *(const float4*)&o_ws[(size_t)(row0 + r) * 512 + c4 * 4];
  }
  __syncthreads();
  const int j = tid & 63;
  const int rg = tid >> 6;  // 0..3
  float acc[4] = {0.f, 0.f, 0.f, 0.f};
  for (int c = 0; c < 512; ++c) {
    const float w = Wu[c * 64 + j];
#pragma unroll
    for (int r = 0; r < 4; ++r) acc[r] += xs[rg * 4 + r][c] * w;
  }
  const float bias = bu[j];
#pragma unroll
  for (int r = 0; r < 4; ++r)
    out[(size_t)(row0 + rg * 4 + r) * 64 + j] = acc[r] + bias;
}

extern "C" void kernel_launch(void* const* d_in, const int* in_sizes, int n_in,
                              void* d_out, int out_size, void* d_ws, size_t ws_size,
                              hipStream_t stream) {
  const float* values  = (const float*)d_in[0];
  const float* keys    = (const float*)d_in[1];
  const float* queries = (const float*)d_in[2];
  const float* Wv      = (const float*)d_in[3];
  const float* Wk      = (const float*)d_in[4];
  const float* Wq      = (const float*)d_in[5];
  const float* Wu      = (const float*)d_in[6];
  const float* bu      = (const float*)d_in[7];
  float* out = (float*)d_out;

  float* ws = (float*)d_ws;
  const size_t NQ = (size_t)B_ * H_ * T_ * E_;  // 4.19M floats each
  float* q_ws = ws;
  float* k_ws = q_ws + NQ;
  float* v_ws = k_ws + NQ;
  float* o_ws = v_ws + NQ;                      // (b,t,h,e)
  float* m_ws = o_ws + NQ;                      // B*H*T
  float* s_ws = m_ws + (size_t)B_ * H_ * T_;

  // projections (scale folded into Q)
  proj_kernel<<<B_ * T_ / 8, 512, 0, stream>>>(queries, Wq, q_ws, SCALE_);
  proj_kernel<<<B_ * T_ / 8, 512, 0, stream>>>(keys, Wk, k_ws, 1.0f);
  proj_kernel<<<B_ * T_ / 8, 512, 0, stream>>>(values, Wv, v_ws, 1.0f);

  // pass A: column-softmax stats (over t) per (b,h,d)
  stats_kernel<<<dim3(T_ / 64, B_ * H_), 256, 0, stream>>>(k_ws, q_ws, m_ws, s_ws);

  // pass B: normalized P^T V
  apply_kernel<<<dim3(T_ / 64, B_ * H_), 256, 0, stream>>>(k_ws, q_ws, v_ws,
                                                           m_ws, s_ws, o_ws);

  // output projection
  unify_kernel<<<B_ * T_ / 16, 256, 0, stream>>>(o_ws, Wu, bu, out);
}

// Round 2
// 308.537 us; speedup vs baseline: 3.3305x; 3.3305x over previous
//
#include <hip/hip_runtime.h>
#include <hip/hip_bf16.h>

// ---------------------------------------------------------------------------
// Column-softmax self-attention, bf16 MFMA pipeline.
//   S[d,t] = k_d . q_t * (1/8)  (scale folded into Q proj; |S| <= ~3 so no max
//   subtraction needed)  P[d,t] = exp(S)/s_d, s_d = sum_t exp(S[d,t])
//   out[t,e] = sum_d exp(S[d,t]) * V'[d,e],  V'[d,e] = v[d,e]/s_d  (pre-folded)
// MFMA 16x16x32 bf16:
//   A: lane holds A[m=lane%16][k=(lane/16)*8+j]   (row-major, 8 contig k)
//   B: lane holds B[k=(lane/16)*8+j][n=lane%16]   (same pattern from [n][k] storage)
//   C/D: lane holds D[row=(lane/16)*4+r][col=lane%16]
// ---------------------------------------------------------------------------

typedef __attribute__((ext_vector_type(8))) __bf16 bf16x8;
typedef __attribute__((ext_vector_type(8))) unsigned short ushort8;
typedef __attribute__((ext_vector_type(4))) float f32x4;
typedef unsigned int uint32;

constexpr int B_ = 4;
constexpr int T_ = 2048;
constexpr int H_ = 8;
constexpr int E_ = 64;
constexpr int BH_ = B_ * H_;
constexpr float SCALE_ = 0.125f;  // 1/sqrt(64)

__device__ inline uint32 f2bf1(float f) {  // fp32 -> bf16 bits, RNE
  uint32 u = __builtin_bit_cast(uint32, f);
  return (u + 0x7fffu + ((u >> 16) & 1u)) >> 16;
}
__device__ inline uint32 pk2(float a, float b) {
  return f2bf1(a) | (f2bf1(b) << 16);
}
__device__ inline bf16x8 ld8(const unsigned short* p) {
  return __builtin_bit_cast(bf16x8, *(const ushort8*)p);
}
#define MFMA16(a, b, c) __builtin_amdgcn_mfma_f32_16x16x32_bf16(a, b, c, 0, 0, 0)

// ---- projection -> bf16 (b,h,t,e) layout, scale folded
__global__ __launch_bounds__(512) void proj_bf16_kernel(
    const float* __restrict__ X, const float* __restrict__ W,
    unsigned short* __restrict__ Y, float scale) {
  constexpr int RT = 8;
  __shared__ float xs[RT][E_];
  const int row0 = blockIdx.x * RT;  // row = b*T + t
  const int tid = threadIdx.x;
  {
    const int r = tid >> 6, c = tid & 63;
    xs[r][c] = X[(row0 + r) * E_ + c];
  }
  __syncthreads();
  const int j = tid;
  const int h = j >> 6, e = j & 63;
  float acc[RT];
#pragma unroll
  for (int r = 0; r < RT; ++r) acc[r] = 0.f;
  for (int c = 0; c < E_; ++c) {
    const float w = W[c * (H_ * E_) + j];
#pragma unroll
    for (int r = 0; r < RT; ++r) acc[r] += xs[r][c] * w;
  }
#pragma unroll
  for (int r = 0; r < RT; ++r) {
    const int row = row0 + r;
    const int b = row >> 11, t = row & (T_ - 1);
    Y[(((size_t)(b * H_ + h) * T_ + t) << 6) + e] =
        (unsigned short)f2bf1(acc[r] * scale);
  }
}

// ---- projection -> fp32 (for V, scaled later by 1/s_d)
__global__ __launch_bounds__(512) void proj_f32_kernel(
    const float* __restrict__ X, const float* __restrict__ W,
    float* __restrict__ Y) {
  constexpr int RT = 8;
  __shared__ float xs[RT][E_];
  const int row0 = blockIdx.x * RT;
  const int tid = threadIdx.x;
  {
    const int r = tid >> 6, c = tid & 63;
    xs[r][c] = X[(row0 + r) * E_ + c];
  }
  __syncthreads();
  const int j = tid;
  const int h = j >> 6, e = j & 63;
  float acc[RT];
#pragma unroll
  for (int r = 0; r < RT; ++r) acc[r] = 0.f;
  for (int c = 0; c < E_; ++c) {
    const float w = W[c * (H_ * E_) + j];
#pragma unroll
    for (int r = 0; r < RT; ++r) acc[r] += xs[r][c] * w;
  }
#pragma unroll
  for (int r = 0; r < RT; ++r) {
    const int row = row0 + r;
    const int b = row >> 11, t = row & (T_ - 1);
    Y[(((size_t)(b * H_ + h) * T_ + t) << 6) + e] = acc[r];
  }
}

// ---- pass A: s_inv[bh][d] = 1 / sum_t exp(S[d,t]); wave owns 64 d rows
__global__ __launch_bounds__(256) void stats_kernel(
    const unsigned short* __restrict__ K16, const unsigned short* __restrict__ Q16,
    float* __restrict__ s_inv) {
  const int bh = blockIdx.y;
  const int tid = threadIdx.x;
  const int w = tid >> 6, lane = tid & 63;
  const int lm = lane & 15, lq = lane >> 4;
  const int d0 = blockIdx.x * 256 + w * 64;
  const unsigned short* Kp = K16 + (size_t)bh * T_ * E_;
  const unsigned short* Qp = Q16 + (size_t)bh * T_ * E_;

  bf16x8 kf[4][2];
#pragma unroll
  for (int dt = 0; dt < 4; ++dt) {
    kf[dt][0] = ld8(&Kp[(size_t)(d0 + dt * 16 + lm) * E_ + lq * 8]);
    kf[dt][1] = ld8(&Kp[(size_t)(d0 + dt * 16 + lm) * E_ + 32 + lq * 8]);
  }
  f32x4 sacc[4];
#pragma unroll
  for (int dt = 0; dt < 4; ++dt) sacc[dt] = (f32x4){0.f, 0.f, 0.f, 0.f};
  const f32x4 zero = {0.f, 0.f, 0.f, 0.f};

  for (int t0 = 0; t0 < T_; t0 += 16) {
    bf16x8 ql = ld8(&Qp[(size_t)(t0 + lm) * E_ + lq * 8]);
    bf16x8 qh = ld8(&Qp[(size_t)(t0 + lm) * E_ + 32 + lq * 8]);
#pragma unroll
    for (int dt = 0; dt < 4; ++dt) {
      f32x4 c = MFMA16(kf[dt][0], ql, zero);
      c = MFMA16(kf[dt][1], qh, c);
#pragma unroll
      for (int r = 0; r < 4; ++r) sacc[dt][r] += __expf(c[r]);
    }
  }
  // reduce over the 16 column-lanes
#pragma unroll
  for (int m = 1; m < 16; m <<= 1) {
#pragma unroll
    for (int dt = 0; dt < 4; ++dt)
#pragma unroll
      for (int r = 0; r < 4; ++r)
        sacc[dt][r] += __shfl_xor(sacc[dt][r], m);
  }
  if (lm == 0) {
#pragma unroll
    for (int dt = 0; dt < 4; ++dt)
#pragma unroll
      for (int r = 0; r < 4; ++r)
        s_inv[(size_t)bh * T_ + d0 + dt * 16 + lq * 4 + r] = 1.0f / sacc[dt][r];
  }
}

// ---- scale+transpose: Vt[bh][e][d] = v[bh][d][e] * s_inv[d]  (bf16)
__global__ __launch_bounds__(256) void scale_kernel(
    const float* __restrict__ Vf, const float* __restrict__ s_inv,
    unsigned short* __restrict__ Vt16) {
  __shared__ float ts[64][68];
  const int bh = blockIdx.y;
  const int d0 = blockIdx.x * 64;
  const float* Vp = Vf + (size_t)bh * T_ * E_;
  const int tid = threadIdx.x;
  for (int idx = tid; idx < 64 * 16; idx += 256) {
    const int r = idx >> 4, c4 = idx & 15;
    const float4 v = *(const float4*)&Vp[(size_t)(d0 + r) * E_ + c4 * 4];
    const float is = s_inv[(size_t)bh * T_ + d0 + r];
    ts[r][c4 * 4 + 0] = v.x * is;
    ts[r][c4 * 4 + 1] = v.y * is;
    ts[r][c4 * 4 + 2] = v.z * is;
    ts[r][c4 * 4 + 3] = v.w * is;
  }
  __syncthreads();
  for (int idx = tid; idx < 64 * 16; idx += 256) {
    const int e = idx >> 4, d4 = idx & 15;
    uint2 o;
    o.x = pk2(ts[d4 * 4 + 0][e], ts[d4 * 4 + 1][e]);
    o.y = pk2(ts[d4 * 4 + 2][e], ts[d4 * 4 + 3][e]);
    *(uint2*)&Vt16[((size_t)bh * E_ + e) * T_ + d0 + d4 * 4] = o;
  }
}

// ---- pass B: O[t,e] = sum_d exp(S[d,t]) * V'[d,e]; wave owns 32 t x 64 e
__global__ __launch_bounds__(256) void apply_kernel(
    const unsigned short* __restrict__ K16, const unsigned short* __restrict__ Q16,
    const unsigned short* __restrict__ Vt16, float* __restrict__ o_ws) {
  __shared__ unsigned short es[4][32][40];  // per-wave E^T scratch, stride 40 (80 B)
  const int bh = blockIdx.y;
  const int b = bh >> 3, h = bh & 7;
  const int tid = threadIdx.x;
  const int w = tid >> 6, lane = tid & 63;
  const int lm = lane & 15, lq = lane >> 4;
  const int t0 = blockIdx.x * 128 + w * 32;
  const unsigned short* Kp = K16 + (size_t)bh * T_ * E_;
  const unsigned short* Qp = Q16 + (size_t)bh * T_ * E_;
  const unsigned short* Vp = Vt16 + (size_t)bh * E_ * T_;

  bf16x8 qf[2][2];  // loop-invariant Q fragments (B operand, n=t)
#pragma unroll
  for (int tt = 0; tt < 2; ++tt) {
    qf[tt][0] = ld8(&Qp[(size_t)(t0 + tt * 16 + lm) * E_ + lq * 8]);
    qf[tt][1] = ld8(&Qp[(size_t)(t0 + tt * 16 + lm) * E_ + 32 + lq * 8]);
  }
  f32x4 acc[2][4];
#pragma unroll
  for (int tt = 0; tt < 2; ++tt)
#pragma unroll
    for (int ec = 0; ec < 4; ++ec) acc[tt][ec] = (f32x4){0.f, 0.f, 0.f, 0.f};
  const f32x4 zero = {0.f, 0.f, 0.f, 0.f};

  for (int d0 = 0; d0 < T_; d0 += 32) {
    const bf16x8 k0l = ld8(&Kp[(size_t)(d0 + lm) * E_ + lq * 8]);
    const bf16x8 k0h = ld8(&Kp[(size_t)(d0 + lm) * E_ + 32 + lq * 8]);
    const bf16x8 k1l = ld8(&Kp[(size_t)(d0 + 16 + lm) * E_ + lq * 8]);
    const bf16x8 k1h = ld8(&Kp[(size_t)(d0 + 16 + lm) * E_ + 32 + lq * 8]);
    bf16x8 vf[4];
#pragma unroll
    for (int ec = 0; ec < 4; ++ec)
      vf[ec] = ld8(&Vp[(size_t)(ec * 16 + lm) * T_ + d0 + lq * 8]);

#pragma unroll
    for (int tt = 0; tt < 2; ++tt) {
      f32x4 c0 = MFMA16(k0l, qf[tt][0], zero);
      c0 = MFMA16(k0h, qf[tt][1], c0);
      f32x4 c1 = MFMA16(k1l, qf[tt][0], zero);
      c1 = MFMA16(k1h, qf[tt][1], c1);
      // E = exp(S), packed bf16, stored transposed: es[t][d]
      float e0[4], e1[4];
#pragma unroll
      for (int r = 0; r < 4; ++r) { e0[r] = __expf(c0[r]); e1[r] = __expf(c1[r]); }
      *(uint2*)&es[w][tt * 16 + lm][lq * 4] =
          make_uint2(pk2(e0[0], e0[1]), pk2(e0[2], e0[3]));
      *(uint2*)&es[w][tt * 16 + lm][16 + lq * 4] =
          make_uint2(pk2(e1[0], e1[1]), pk2(e1[2], e1[3]));
    }
    // wave-private LDS: only need our own DS writes drained (lockstep wave)
    asm volatile("s_waitcnt lgkmcnt(0)" ::: "memory");
#pragma unroll
    for (int tt = 0; tt < 2; ++tt) {
      const bf16x8 ae = ld8(&es[w][tt * 16 + lm][lq * 8]);  // A: [m=t][k=d]
#pragma unroll
      for (int ec = 0; ec < 4; ++ec)
        acc[tt][ec] = MFMA16(ae, vf[ec], acc[tt][ec]);
    }
  }

  // epilogue: o_ws in (b,t,h,e) fp32
#pragma unroll
  for (int tt = 0; tt < 2; ++tt) {
    const int t = t0 + tt * 16 + lq * 4;
#pragma unroll
    for (int ec = 0; ec < 4; ++ec) {
      const int e = ec * 16 + lm;
      float* op = &o_ws[((size_t)(b * T_ + t) * H_ + h) * E_ + e];
#pragma unroll
      for (int r = 0; r < 4; ++r) op[(size_t)r * H_ * E_] = acc[tt][ec][r];
    }
  }
}

// ---- unify: out[row, j] = sum_c o_ws[row, c] * Wu[c, j] + bu[j]
__global__ __launch_bounds__(256) void unify_kernel(
    const float* __restrict__ o_ws, const float* __restrict__ Wu,
    const float* __restrict__ bu, float* __restrict__ out) {
  constexpr int RT = 16;
  __shared__ float xs[RT][H_ * E_];
  const int row0 = blockIdx.x * RT;
  const int tid = threadIdx.x;
  for (int idx = tid; idx < RT * 128; idx += 256) {
    const int r = idx >> 7, c4 = idx & 127;
    *(float4*)&xs[r][c4 * 4] = *(const float4*)&o_ws[(size_t)(row0 + r) * 512 + c4 * 4];
  }
  __syncthreads();
  const int j = tid & 63;
  const int rg = tid >> 6;
  float acc[4] = {0.f, 0.f, 0.f, 0.f};
  for (int c = 0; c < 512; ++c) {
    const float w = Wu[c * 64 + j];
#pragma unroll
    for (int r = 0; r < 4; ++r) acc[r] += xs[rg * 4 + r][c] * w;
  }
  const float bias = bu[j];
#pragma unroll
  for (int r = 0; r < 4; ++r)
    out[(size_t)(row0 + rg * 4 + r) * 64 + j] = acc[r] + bias;
}

extern "C" void kernel_launch(void* const* d_in, const int* in_sizes, int n_in,
                              void* d_out, int out_size, void* d_ws, size_t ws_size,
                              hipStream_t stream) {
  const float* values  = (const float*)d_in[0];
  const float* keys    = (const float*)d_in[1];
  const float* queries = (const float*)d_in[2];
  const float* Wv      = (const float*)d_in[3];
  const float* Wk      = (const float*)d_in[4];
  const float* Wq      = (const float*)d_in[5];
  const float* Wu      = (const float*)d_in[6];
  const float* bu      = (const float*)d_in[7];
  float* out = (float*)d_out;

  const size_t NQ = (size_t)BH_ * T_ * E_;  // 4.19M elements
  unsigned short* q_bf = (unsigned short*)d_ws;
  unsigned short* k_bf = q_bf + NQ;
  unsigned short* vt_bf = k_bf + NQ;
  float* v_f  = (float*)(vt_bf + NQ);
  float* o_ws = v_f + NQ;
  float* s_inv = o_ws + NQ;

  proj_bf16_kernel<<<B_ * T_ / 8, 512, 0, stream>>>(queries, Wq, q_bf, SCALE_);
  proj_bf16_kernel<<<B_ * T_ / 8, 512, 0, stream>>>(keys, Wk, k_bf, 1.0f);
  proj_f32_kernel<<<B_ * T_ / 8, 512, 0, stream>>>(values, Wv, v_f);

  stats_kernel<<<dim3(T_ / 256, BH_), 256, 0, stream>>>(k_bf, q_bf, s_inv);
  scale_kernel<<<dim3(T_ / 64, BH_), 256, 0, stream>>>(v_f, s_inv, vt_bf);
  apply_kernel<<<dim3(T_ / 128, BH_), 256, 0, stream>>>(k_bf, q_bf, vt_bf, o_ws);
  unify_kernel<<<B_ * T_ / 16, 256, 0, stream>>>(o_ws, Wu, bu, out);
}